// Round 9
// baseline (600.026 us; speedup 1.0000x reference)
//
#include <hip/hip_runtime.h>

// z <- tanh(z @ W^T + x), 50 fixed-point steps. B=16384, D=512.
// Round 9: TM=64 (round-8's TM=32/2-blocks regressed: W L2 stream doubled,
// MfmaUtil fell), double-buffered z (2 x 64 KB LDS), ONE barrier/iter.
// NEW: j-tile-split gemm with WOVEN epilogue. Waves issue in-order, so
// [128 MFMA][epi VALU] serializes the pipes (round-7: MfmaUtil 42 +
// VALUBusy 38, neither saturated). Split: tile0 gemm (p0/p1, 32 ks) ->
// tile1 gemm (q0/q1) with tile0's epilogue woven in per 4-ks chunk ->
// tile1 epilogue -> barrier. The woven VALU (~110 cyc/chunk) hides under
// tile1's MFMA issue (~256 cyc/chunk). Cost: tile1 re-reads b0/b1 (LDS
// reads x2, still under MFMA pipe time; bank conflicts rise ~1.5x).
// x in 32 packed-fp16 VGPRs (loaded once; per-iter global x reads thrash
// L2 -- round 5/6 evidence). W pre-scaled by K = 2*log2(e) as bf16 MFMA
// A-fragments in d_ws (L2-resident; register-resident W impossible:
// 128 arch-VGPR cap). tanh = 1 - 2/(exp2(s)+1), NO clamp (|s| < 128
// always; round-8 verified). Pack via v_cvt_pk_bf16_f32.
// Reg budget peak (weave): p 32 + q 32 + x 32 + staging/addr ~24 = ~120.

typedef short s8v  __attribute__((ext_vector_type(8)));   // 8 bf16 = 4 VGPRs
typedef float f32x16 __attribute__((ext_vector_type(16)));
typedef _Float16 h4 __attribute__((ext_vector_type(4)));  // 4 fp16 = 2 VGPRs

#define BATCH 16384
#define DIM   512
#define TM    64        // rows per block
#define NITER 50        // 1 init step + 49 GEMM steps

#define KSC 2.8853900817779268f    // 2*log2(e)

__device__ __forceinline__ unsigned short f2bf(float f) {
    unsigned int u = __float_as_uint(f);
    u += 0x7fffu + ((u >> 16) & 1u);          // round-to-nearest-even
    return (unsigned short)(u >> 16);
}

// W (fp32 [512][512] row-major) -> K-prescaled bf16 A-fragments for
// v_mfma_f32_32x32x16_bf16. Granule tid = (jt*32 + ks)*64 + lane holds
// K*W[j = 32*jt + (lane&31)][k = 16*ks + 8*(lane>>5) .. +8] as 16 B.
__global__ void wprep_kernel(const float* __restrict__ W, unsigned short* __restrict__ Wf) {
    int tid = blockIdx.x * blockDim.x + threadIdx.x;   // 0..32767
    int jt  = tid >> 11;
    int rem = tid & 2047;
    int ks  = rem >> 6;
    int L   = rem & 63;
    int j   = jt * 32 + (L & 31);
    int k   = ks * 16 + (L >> 5) * 8;
    const float* src = W + j * DIM + k;
    uint4 p;
    p.x = (unsigned)f2bf(src[0] * KSC) | ((unsigned)f2bf(src[1] * KSC) << 16);
    p.y = (unsigned)f2bf(src[2] * KSC) | ((unsigned)f2bf(src[3] * KSC) << 16);
    p.z = (unsigned)f2bf(src[4] * KSC) | ((unsigned)f2bf(src[5] * KSC) << 16);
    p.w = (unsigned)f2bf(src[6] * KSC) | ((unsigned)f2bf(src[7] * KSC) << 16);
    ((uint4*)Wf)[tid] = p;
}

// LDS z layout: row r x 512 bf16, 64 chunks of 16 B per row, XOR swizzle
// chunk' = chunk ^ (r & 7) -> spreads bank groups for ds_read_b128 / writes.
__device__ __forceinline__ int z_addr(int r, int j) {   // element index
    int c  = j >> 3;
    int lo = j & 7;
    return r * DIM + (((c ^ (r & 7)) << 3) | lo);
}

__device__ __forceinline__ unsigned pk_bf16(float lo, float hi) {
    unsigned r;
    asm("v_cvt_pk_bf16_f32 %0, %1, %2" : "=v"(r) : "v"(lo), "v"(hi));  // RNE
    return r;
}

// s is the ALREADY K-SCALED argument: tanh(v) where s = K*v. No clamp:
// reachable |s| < 128, exp2 finite (or rcp limit gives exactly +-1).
__device__ __forceinline__ float tanh_pre(float s) {
    float t = __builtin_amdgcn_exp2f(s);
    float q = __builtin_amdgcn_rcpf(t + 1.0f);
    return fmaf(-2.0f, q, 1.0f);            // (t-1)/(t+1) == 1 - 2/(t+1)
}

__device__ __forceinline__ f32x16 zero16() {
    f32x16 v;
#pragma unroll
    for (int i = 0; i < 16; ++i) v[i] = 0.0f;
    return v;
}

__device__ __forceinline__ h4 cvt_h4(float4 t) {
    h4 r;
    r[0] = (_Float16)t.x; r[1] = (_Float16)t.y;
    r[2] = (_Float16)t.z; r[3] = (_Float16)t.w;
    return r;
}

__global__ __launch_bounds__(512, 2)
void fixpoint_kernel(const float* __restrict__ x,
                     const unsigned short* __restrict__ Wf,
                     float* __restrict__ out) {
    __shared__ alignas(16) unsigned short zt[2][TM * DIM];   // 128 KB double buffer

    const int tid  = threadIdx.x;
    const int lane = tid & 63;
    const int w    = tid >> 6;       // wave 0..7, owns j-slab [64w, 64w+64)
    const int l31  = lane & 31;
    const int h    = lane >> 5;      // k-half for A/B fragments
    const int r0   = blockIdx.x * TM;
    const int jt0  = 2 * w;
    const int jb0  = 64 * w;
    const int swz  = l31 & 7;        // z-row swizzle key

    const s8v* Wfv = (const s8v*)Wf;

    // ---- x -> 32 packed-fp16 VGPRs, fragment order (the ONLY global x read) ----
    // xf0[g]: row l31 cols jb0+8g+4h.. ; xf1: row l31+32 ; xf2/xf3: cols +32.
    h4 xf0[4], xf1[4], xf2[4], xf3[4];
    {
        const float* xr0 = x + (size_t)(r0 + l31) * DIM;
        const float* xr1 = x + (size_t)(r0 + l31 + 32) * DIM;
#pragma unroll
        for (int g = 0; g < 4; ++g) {
            const int j0 = jb0 + 8 * g + 4 * h;
            xf0[g] = cvt_h4(*(const float4*)&xr0[j0]);
            xf1[g] = cvt_h4(*(const float4*)&xr1[j0]);
            xf2[g] = cvt_h4(*(const float4*)&xr0[j0 + 32]);
            xf3[g] = cvt_h4(*(const float4*)&xr1[j0 + 32]);
        }
    }

    f32x16 p0, p1, q0, q1;   // tile0 / tile1 accumulators

    // One epi quarter-group: 4 elements of acc A (regs 4g..4g+3) -> bf16 pair
    // write at row, cols jb0 + tb + 8g + 4h. acc layout: col=lane&31 -> z-row;
    // row=(reg&3)+8*(reg>>2)+4h -> j.
    auto epi_q = [&](unsigned short* __restrict__ zn, int tb, int g,
                     const f32x16& A, int row, h4 xg) {
        const int j0 = jb0 + tb + 8 * g + 4 * h;
        uint2 pv;
        pv.x = pk_bf16(tanh_pre(fmaf((float)xg[0], KSC, A[4*g+0])),
                       tanh_pre(fmaf((float)xg[1], KSC, A[4*g+1])));
        pv.y = pk_bf16(tanh_pre(fmaf((float)xg[2], KSC, A[4*g+2])),
                       tanh_pre(fmaf((float)xg[3], KSC, A[4*g+3])));
        *(uint2*)&zn[z_addr(row, j0)] = pv;
    };

    // tile 0 gemm: plain 32-ks loop
    auto gemm0 = [&](const unsigned short* __restrict__ zc) {
        p0 = zero16(); p1 = zero16();
#pragma unroll 4
        for (int ks = 0; ks < 32; ++ks) {
            s8v a = Wfv[(jt0 * 32 + ks) * 64 + lane];
            const int c = ((2 * ks + h) ^ swz) << 3;
            s8v b0 = *(const s8v*)&zc[l31 * DIM + c];
            s8v b1 = *(const s8v*)&zc[(l31 + 32) * DIM + c];
            p0 = __builtin_amdgcn_mfma_f32_32x32x16_bf16(a, b0, p0, 0, 0, 0);
            p1 = __builtin_amdgcn_mfma_f32_32x32x16_bf16(a, b1, p1, 0, 0, 0);
        }
    };

    // tile 1 gemm with tile-0 epilogue WOVEN in: 8 chunks of (4 ks + 1 epi_q).
    // Static interleave -> in-order wave issues epi VALU between MFMA bursts.
    auto gemm1_weave = [&](const unsigned short* __restrict__ zc,
                           unsigned short* __restrict__ zn) {
        q0 = zero16(); q1 = zero16();
#pragma unroll
        for (int ch = 0; ch < 8; ++ch) {
#pragma unroll
            for (int k2 = 0; k2 < 4; ++k2) {
                const int ks = ch * 4 + k2;
                s8v a = Wfv[((jt0 + 1) * 32 + ks) * 64 + lane];
                const int c = ((2 * ks + h) ^ swz) << 3;
                s8v b0 = *(const s8v*)&zc[l31 * DIM + c];
                s8v b1 = *(const s8v*)&zc[(l31 + 32) * DIM + c];
                q0 = __builtin_amdgcn_mfma_f32_32x32x16_bf16(a, b0, q0, 0, 0, 0);
                q1 = __builtin_amdgcn_mfma_f32_32x32x16_bf16(a, b1, q1, 0, 0, 0);
            }
            const int g = ch >> 1;
            if ((ch & 1) == 0) epi_q(zn, 0, g, p0, l31,      xf0[g]);
            else               epi_q(zn, 0, g, p1, l31 + 32, xf1[g]);
        }
    };

    auto epi_out = [&]() {
        float* o0 = out + (size_t)(r0 + l31) * DIM;
        float* o1 = out + (size_t)(r0 + l31 + 32) * DIM;
#pragma unroll
        for (int g = 0; g < 4; ++g) {
            const int j0 = jb0 + 8 * g + 4 * h;
            float4 v;
            v.x = tanh_pre(fmaf((float)xf0[g][0], KSC, p0[4*g+0]));
            v.y = tanh_pre(fmaf((float)xf0[g][1], KSC, p0[4*g+1]));
            v.z = tanh_pre(fmaf((float)xf0[g][2], KSC, p0[4*g+2]));
            v.w = tanh_pre(fmaf((float)xf0[g][3], KSC, p0[4*g+3]));
            *(float4*)&o0[j0] = v;
            v.x = tanh_pre(fmaf((float)xf1[g][0], KSC, p1[4*g+0]));
            v.y = tanh_pre(fmaf((float)xf1[g][1], KSC, p1[4*g+1]));
            v.z = tanh_pre(fmaf((float)xf1[g][2], KSC, p1[4*g+2]));
            v.w = tanh_pre(fmaf((float)xf1[g][3], KSC, p1[4*g+3]));
            *(float4*)&o1[j0] = v;
            v.x = tanh_pre(fmaf((float)xf2[g][0], KSC, q0[4*g+0]));
            v.y = tanh_pre(fmaf((float)xf2[g][1], KSC, q0[4*g+1]));
            v.z = tanh_pre(fmaf((float)xf2[g][2], KSC, q0[4*g+2]));
            v.w = tanh_pre(fmaf((float)xf2[g][3], KSC, q0[4*g+3]));
            *(float4*)&o0[j0 + 32] = v;
            v.x = tanh_pre(fmaf((float)xf3[g][0], KSC, q1[4*g+0]));
            v.y = tanh_pre(fmaf((float)xf3[g][1], KSC, q1[4*g+1]));
            v.z = tanh_pre(fmaf((float)xf3[g][2], KSC, q1[4*g+2]));
            v.w = tanh_pre(fmaf((float)xf3[g][3], KSC, q1[4*g+3]));
            *(float4*)&o1[j0 + 32] = v;
        }
    };

    // ---- step 1: z0 = tanh(K*x) via the epi path with zero acc ----
    p0 = zero16(); p1 = zero16();
#pragma unroll
    for (int g = 0; g < 4; ++g) {
        epi_q(zt[0], 0,  g, p0, l31,      xf0[g]);
        epi_q(zt[0], 0,  g, p1, l31 + 32, xf1[g]);
        epi_q(zt[0], 32, g, p0, l31,      xf2[g]);
        epi_q(zt[0], 32, g, p1, l31 + 32, xf3[g]);
    }
    __syncthreads();

    int cur = 0;
#pragma unroll 1
    for (int it = 0; it < NITER - 2; ++it) {     // 48 LDS->LDS steps
        unsigned short* zn = zt[cur ^ 1];
        gemm0(zt[cur]);
        gemm1_weave(zt[cur], zn);                // epi tile0 hidden under tile1 MFMA
#pragma unroll
        for (int g = 0; g < 4; ++g) {            // epi tile1 (serial tail)
            epi_q(zn, 32, g, q0, l31,      xf2[g]);
            epi_q(zn, 32, g, q1, l31 + 32, xf3[g]);
        }
        __syncthreads();      // single barrier: writes visible, flip together
        cur ^= 1;
    }
    // ---- step 50: fp32 store to out (weave target is dead scratch) ----
    gemm0(zt[cur]);
    gemm1_weave(zt[cur], zt[cur ^ 1]);
    epi_out();
}

extern "C" void kernel_launch(void* const* d_in, const int* in_sizes, int n_in,
                              void* d_out, int out_size, void* d_ws, size_t ws_size,
                              hipStream_t stream) {
    const float* x = (const float*)d_in[0];   // [16384, 512] fp32
    const float* W = (const float*)d_in[1];   // [512, 512] fp32
    float* out = (float*)d_out;               // [16384, 512] fp32
    unsigned short* Wf = (unsigned short*)d_ws;   // 512 KB bf16 fragments (K-prescaled)

    wprep_kernel<<<128, 256, 0, stream>>>(W, Wf);
    fixpoint_kernel<<<BATCH / TM, 512, 0, stream>>>(x, Wf, out);
}

// Round 10
// 506.630 us; speedup vs baseline: 1.1843x; 1.1843x over previous
//
#include <hip/hip_runtime.h>

// z <- tanh(z @ W^T + x), 50 fixed-point steps. B=16384, D=512.
// Round 10: TM=64 but ONE 1024-thread block per CU (16 waves, 4 waves/SIMD).
// Round-7 (8 waves, 2/SIMD) left 9.7 us/iter vs ~4 us of summed pipe-busy ->
// latency-exposure at low occupancy. Round-8's 4-waves/SIMD test was
// confounded by doubling W L2 traffic (2 blocks); here W stays read ONCE per
// CU per iter: each wave owns a 32-j slab (A = 32 KB/wave, 512 KB/CU) and
// computes 32j x 64r (accs ac0/ac1). Known cost: B ds_reads double
// (every wave reads all 64 z-rows -> 1 MB/CU/iter, conflicts ~2x) -- LDS has
// a dedicated per-CU port and short latency, unlike round-8's shared-L2 hit.
// Double-buffered z (2 x 64 KB), ONE barrier/iter. ks=0/1 A-fragments
// hoisted (iteration-invariant) so gemm starts without an L2 wait.
// x in 16 packed-fp16 VGPRs (loaded once; per-iter global x reads thrash L2,
// rounds 5/6). W pre-scaled by K = 2*log2(e), bf16 MFMA A-fragments in d_ws.
// tanh = 1 - 2/(exp2(s)+1), no clamp (|s| < 128 always; round-8 verified).
// Pack via v_cvt_pk_bf16_f32. Reg budget: acc 32 + x 16 + hoist 8 + ~30 = ~86.

typedef short s8v  __attribute__((ext_vector_type(8)));   // 8 bf16 = 4 VGPRs
typedef float f32x16 __attribute__((ext_vector_type(16)));
typedef _Float16 h4 __attribute__((ext_vector_type(4)));  // 4 fp16 = 2 VGPRs

#define BATCH 16384
#define DIM   512
#define TM    64        // rows per block
#define NITER 50        // 1 init step + 49 GEMM steps

#define KSC 2.8853900817779268f    // 2*log2(e)

__device__ __forceinline__ unsigned short f2bf(float f) {
    unsigned int u = __float_as_uint(f);
    u += 0x7fffu + ((u >> 16) & 1u);          // round-to-nearest-even
    return (unsigned short)(u >> 16);
}

// W (fp32 [512][512] row-major) -> K-prescaled bf16 A-fragments for
// v_mfma_f32_32x32x16_bf16. Granule tid = (jt*32 + ks)*64 + lane holds
// K*W[j = 32*jt + (lane&31)][k = 16*ks + 8*(lane>>5) .. +8] as 16 B.
__global__ void wprep_kernel(const float* __restrict__ W, unsigned short* __restrict__ Wf) {
    int tid = blockIdx.x * blockDim.x + threadIdx.x;   // 0..32767
    int jt  = tid >> 11;
    int rem = tid & 2047;
    int ks  = rem >> 6;
    int L   = rem & 63;
    int j   = jt * 32 + (L & 31);
    int k   = ks * 16 + (L >> 5) * 8;
    const float* src = W + j * DIM + k;
    uint4 p;
    p.x = (unsigned)f2bf(src[0] * KSC) | ((unsigned)f2bf(src[1] * KSC) << 16);
    p.y = (unsigned)f2bf(src[2] * KSC) | ((unsigned)f2bf(src[3] * KSC) << 16);
    p.z = (unsigned)f2bf(src[4] * KSC) | ((unsigned)f2bf(src[5] * KSC) << 16);
    p.w = (unsigned)f2bf(src[6] * KSC) | ((unsigned)f2bf(src[7] * KSC) << 16);
    ((uint4*)Wf)[tid] = p;
}

// LDS z layout: row r x 512 bf16, 64 chunks of 16 B per row, XOR swizzle
// chunk' = chunk ^ (r & 7) -> spreads bank groups for ds_read_b128 / writes.
__device__ __forceinline__ int z_addr(int r, int j) {   // element index
    int c  = j >> 3;
    int lo = j & 7;
    return r * DIM + (((c ^ (r & 7)) << 3) | lo);
}

__device__ __forceinline__ unsigned pk_bf16(float lo, float hi) {
    unsigned r;
    asm("v_cvt_pk_bf16_f32 %0, %1, %2" : "=v"(r) : "v"(lo), "v"(hi));  // RNE
    return r;
}

// s is the ALREADY K-SCALED argument: tanh(v) where s = K*v. No clamp:
// reachable |s| < 128, exp2 finite (or rcp limit gives exactly +-1).
__device__ __forceinline__ float tanh_pre(float s) {
    float t = __builtin_amdgcn_exp2f(s);
    float q = __builtin_amdgcn_rcpf(t + 1.0f);
    return fmaf(-2.0f, q, 1.0f);            // (t-1)/(t+1) == 1 - 2/(t+1)
}

__device__ __forceinline__ f32x16 zero16() {
    f32x16 v;
#pragma unroll
    for (int i = 0; i < 16; ++i) v[i] = 0.0f;
    return v;
}

__device__ __forceinline__ h4 cvt_h4(float4 t) {
    h4 r;
    r[0] = (_Float16)t.x; r[1] = (_Float16)t.y;
    r[2] = (_Float16)t.z; r[3] = (_Float16)t.w;
    return r;
}

__global__ __launch_bounds__(1024, 4)
void fixpoint_kernel(const float* __restrict__ x,
                     const unsigned short* __restrict__ Wf,
                     float* __restrict__ out) {
    __shared__ alignas(16) unsigned short zt[2][TM * DIM];   // 128 KB double buffer

    const int tid  = threadIdx.x;
    const int lane = tid & 63;
    const int w    = tid >> 6;       // wave 0..15, owns j-slab [32w, 32w+32)
    const int l31  = lane & 31;
    const int h    = lane >> 5;      // k-half for A/B fragments
    const int r0   = blockIdx.x * TM;
    const int jb0  = 32 * w;
    const int swz  = l31 & 7;        // z-row swizzle key

    const s8v* Wfv = (const s8v*)Wf;

    // ---- x -> 16 packed-fp16 VGPRs, fragment order (the ONLY global x read) ----
    // xa[g]: row l31, cols jb0+8g+4h.. ; xb[g]: row l31+32, same cols.
    h4 xa[4], xb[4];
    {
        const float* xr0 = x + (size_t)(r0 + l31) * DIM;
        const float* xr1 = x + (size_t)(r0 + l31 + 32) * DIM;
#pragma unroll
        for (int g = 0; g < 4; ++g) {
            const int j0 = jb0 + 8 * g + 4 * h;
            xa[g] = cvt_h4(*(const float4*)&xr0[j0]);
            xb[g] = cvt_h4(*(const float4*)&xr1[j0]);
        }
    }

    // Iteration-invariant A fragments for ks=0,1 (gemm starts without L2 wait)
    const s8v a_h0 = Wfv[(w * 32 + 0) * 64 + lane];
    const s8v a_h1 = Wfv[(w * 32 + 1) * 64 + lane];

    f32x16 ac0, ac1;   // rows l31-block / l31+32-block of the 32j x 64r tile

    // acc layout: col = lane&31 -> z-row; row = (reg&3)+8*(reg>>2)+4h -> j
    auto epi_z = [&](unsigned short* __restrict__ zn) {
#pragma unroll
        for (int g = 0; g < 4; ++g) {
            const int j0 = jb0 + 8 * g + 4 * h;
            uint2 p;
            p.x = pk_bf16(tanh_pre(fmaf((float)xa[g][0], KSC, ac0[4*g+0])),
                          tanh_pre(fmaf((float)xa[g][1], KSC, ac0[4*g+1])));
            p.y = pk_bf16(tanh_pre(fmaf((float)xa[g][2], KSC, ac0[4*g+2])),
                          tanh_pre(fmaf((float)xa[g][3], KSC, ac0[4*g+3])));
            *(uint2*)&zn[z_addr(l31, j0)] = p;
            p.x = pk_bf16(tanh_pre(fmaf((float)xb[g][0], KSC, ac1[4*g+0])),
                          tanh_pre(fmaf((float)xb[g][1], KSC, ac1[4*g+1])));
            p.y = pk_bf16(tanh_pre(fmaf((float)xb[g][2], KSC, ac1[4*g+2])),
                          tanh_pre(fmaf((float)xb[g][3], KSC, ac1[4*g+3])));
            *(uint2*)&zn[z_addr(l31 + 32, j0)] = p;
        }
    };

    auto epi_out = [&]() {
        float* o0 = out + (size_t)(r0 + l31) * DIM;
        float* o1 = out + (size_t)(r0 + l31 + 32) * DIM;
#pragma unroll
        for (int g = 0; g < 4; ++g) {
            const int j0 = jb0 + 8 * g + 4 * h;
            float4 v;
            v.x = tanh_pre(fmaf((float)xa[g][0], KSC, ac0[4*g+0]));
            v.y = tanh_pre(fmaf((float)xa[g][1], KSC, ac0[4*g+1]));
            v.z = tanh_pre(fmaf((float)xa[g][2], KSC, ac0[4*g+2]));
            v.w = tanh_pre(fmaf((float)xa[g][3], KSC, ac0[4*g+3]));
            *(float4*)&o0[j0] = v;
            v.x = tanh_pre(fmaf((float)xb[g][0], KSC, ac1[4*g+0]));
            v.y = tanh_pre(fmaf((float)xb[g][1], KSC, ac1[4*g+1]));
            v.z = tanh_pre(fmaf((float)xb[g][2], KSC, ac1[4*g+2]));
            v.w = tanh_pre(fmaf((float)xb[g][3], KSC, ac1[4*g+3]));
            *(float4*)&o1[j0] = v;
        }
    };

    auto gemm = [&](const unsigned short* __restrict__ zc) {
        ac0 = zero16(); ac1 = zero16();
        {   // ks = 0, 1 with hoisted A
            int c = (h ^ swz) << 3;
            s8v b0 = *(const s8v*)&zc[l31 * DIM + c];
            s8v b1 = *(const s8v*)&zc[(l31 + 32) * DIM + c];
            ac0 = __builtin_amdgcn_mfma_f32_32x32x16_bf16(a_h0, b0, ac0, 0, 0, 0);
            ac1 = __builtin_amdgcn_mfma_f32_32x32x16_bf16(a_h0, b1, ac1, 0, 0, 0);
            c = ((2 + h) ^ swz) << 3;
            b0 = *(const s8v*)&zc[l31 * DIM + c];
            b1 = *(const s8v*)&zc[(l31 + 32) * DIM + c];
            ac0 = __builtin_amdgcn_mfma_f32_32x32x16_bf16(a_h1, b0, ac0, 0, 0, 0);
            ac1 = __builtin_amdgcn_mfma_f32_32x32x16_bf16(a_h1, b1, ac1, 0, 0, 0);
        }
#pragma unroll 6
        for (int ks = 2; ks < 32; ++ks) {
            s8v a = Wfv[(w * 32 + ks) * 64 + lane];
            const int c = ((2 * ks + h) ^ swz) << 3;
            s8v b0 = *(const s8v*)&zc[l31 * DIM + c];
            s8v b1 = *(const s8v*)&zc[(l31 + 32) * DIM + c];
            ac0 = __builtin_amdgcn_mfma_f32_32x32x16_bf16(a, b0, ac0, 0, 0, 0);
            ac1 = __builtin_amdgcn_mfma_f32_32x32x16_bf16(a, b1, ac1, 0, 0, 0);
        }
    };

    // ---- step 1: z0 = tanh(K*x) via the epi path with zero acc ----
    ac0 = zero16(); ac1 = zero16();
    epi_z(zt[0]);
    __syncthreads();

    int cur = 0;
#pragma unroll 1
    for (int it = 0; it < NITER - 2; ++it) {     // 48 LDS->LDS steps
        gemm(zt[cur]);
        epi_z(zt[cur ^ 1]);   // other buffer: safe vs lagging waves' gemm reads
        __syncthreads();      // single barrier: writes visible, flip together
        cur ^= 1;
    }
    // ---- step 50: fp32 store to out ----
    gemm(zt[cur]);
    epi_out();
}

extern "C" void kernel_launch(void* const* d_in, const int* in_sizes, int n_in,
                              void* d_out, int out_size, void* d_ws, size_t ws_size,
                              hipStream_t stream) {
    const float* x = (const float*)d_in[0];   // [16384, 512] fp32
    const float* W = (const float*)d_in[1];   // [512, 512] fp32
    float* out = (float*)d_out;               // [16384, 512] fp32
    unsigned short* Wf = (unsigned short*)d_ws;   // 512 KB bf16 fragments (K-prescaled)

    wprep_kernel<<<128, 256, 0, stream>>>(W, Wf);
    fixpoint_kernel<<<BATCH / TM, 1024, 0, stream>>>(x, Wf, out);
}